// Round 14
// baseline (153.946 us; speedup 1.0000x reference)
//
#include <hip/hip_runtime.h>
#include <hip/hip_bf16.h>
#include <cstdint>

#define N_NODES 8192
#define DDIM    64
#define DX      128
#define NEDGE   262144
#define BR      128                       // query rows per block (8 waves)
#define BC      64                        // key/value columns per tile
#define SPLITS  8
#define TILES   (N_NODES / BC / SPLITS)   // 16
#define RCAP    64                        // per-row edge bin capacity
// p = exp(S-66) = 2^(fma(S, log2e, -66*log2e)) via raw v_exp_f32
#define L2E     1.44269504f
#define MSH2    95.2178727f

typedef float f32x16 __attribute__((ext_vector_type(16)));
typedef short short8 __attribute__((ext_vector_type(8)));
typedef short short4v __attribute__((ext_vector_type(4)));

__device__ __forceinline__ short f2bf(float f) {
    union { float f; uint32_t u; } v; v.f = f;
    uint32_t u = v.u;
    uint32_t r = (u + 0x7FFFu + ((u >> 16) & 1u)) >> 16;
    return (short)r;
}
__device__ __forceinline__ float bf2f(short s) {
    union { uint32_t u; float f; } v;
    v.u = ((uint32_t)(uint16_t)s) << 16;
    return v.f;
}
__device__ __forceinline__ unsigned cvtpk_bf16(float lo, float hi) {
    unsigned r;
    asm("v_cvt_pk_bf16_f32 %0, %1, %2" : "=v"(r) : "v"(lo), "v"(hi));
    return r;
}
__device__ __forceinline__ float exp2_raw(float x) {
    float r;
    asm("v_exp_f32 %0, %1" : "=v"(r) : "v"(x));   // raw VOP1, no libcall
    return r;
}
__device__ __forceinline__ void gload_lds16(const short* g, short* l) {
    __builtin_amdgcn_global_load_lds(
        (const __attribute__((address_space(1))) unsigned int*)g,
        (__attribute__((address_space(3))) unsigned int*)l, 16, 0, 0);
}

// ---- fused prep: [0,512) X-build (vectorized), [512,768) Y-transpose,
// [768,1792) edge scores + binning.
// Xbf: natural feature order [cos(0..63) | sin(64..127)].
// Ybt: columns stored with j-bits 2<->3 swapped (pi involution) so the S' output
// registers feed PV A-fragments with zero cross-lane exchange (verified r3/6/9-13).
__global__ __launch_bounds__(256) void cpa_prep_all(
    const float* __restrict__ mag, const float* __restrict__ phase,
    const int* __restrict__ ei, const float* __restrict__ ea,
    const float* __restrict__ W, const float* __restrict__ b,
    short* __restrict__ Xbf, short* __restrict__ Ybt,
    short* __restrict__ esb, int* __restrict__ cnt,
    int* __restrict__ keys) {
    __shared__ short tile[64][65];
    __shared__ float wsb[5];
    const int blk = blockIdx.x;
    const int tid = threadIdx.x;
    if (blk < 512) {
        // X-build: 4 features/thread, float4 in, short4 out
        int idx4 = blk * 256 + tid;                // 0..131071
        int i  = idx4 >> 4;
        int dq = (idx4 & 15) << 2;
        float4 m4 = *(const float4*)(mag   + (size_t)i * 64 + dq);
        float4 p4 = *(const float4*)(phase + (size_t)i * 64 + dq);
        short4v c4, s4;
        c4[0] = f2bf(m4.x * __cosf(p4.x)); s4[0] = f2bf(m4.x * __sinf(p4.x));
        c4[1] = f2bf(m4.y * __cosf(p4.y)); s4[1] = f2bf(m4.y * __sinf(p4.y));
        c4[2] = f2bf(m4.z * __cosf(p4.z)); s4[2] = f2bf(m4.z * __sinf(p4.z));
        c4[3] = f2bf(m4.w * __cosf(p4.w)); s4[3] = f2bf(m4.w * __sinf(p4.w));
        *(short4v*)(Xbf + (size_t)i * DX + dq)      = c4;
        *(short4v*)(Xbf + (size_t)i * DX + 64 + dq) = s4;
    } else if (blk < 768) {
        int bb = blk - 512;
        int bi = bb >> 1;
        int bc = bb & 1;
        int i0 = bi * 64;
        const float* src = bc ? phase : mag;
        for (int itr = 0; itr < 16; ++itr) {
            int idx = tid + itr * 256;             // 0..4095
            int ii = idx >> 6, cc = idx & 63;
            tile[ii][cc] = f2bf(src[(size_t)(i0 + ii) * 64 + cc]);
        }
        __syncthreads();
        for (int itr = 0; itr < 16; ++itr) {
            int idx = tid + itr * 256;
            int cc = idx >> 6, ii = idx & 63;
            int jp = (ii & 51) | ((ii & 4) << 1) | ((ii & 8) >> 1);  // swap j bits 2,3
            Ybt[(size_t)(bc * 64 + cc) * N_NODES + i0 + jp] = tile[ii][cc];
        }
    } else {
        if (tid < 64) {
            float w0 = W[tid * 4 + 0], w1 = W[tid * 4 + 1];
            float w2 = W[tid * 4 + 2], w3 = W[tid * 4 + 3];
            float bb = b[tid];
            #pragma unroll
            for (int o = 32; o > 0; o >>= 1) {
                w0 += __shfl_down(w0, o);
                w1 += __shfl_down(w1, o);
                w2 += __shfl_down(w2, o);
                w3 += __shfl_down(w3, o);
                bb += __shfl_down(bb, o);
            }
            if (tid == 0) { wsb[0] = w0; wsb[1] = w1; wsb[2] = w2; wsb[3] = w3; wsb[4] = bb; }
        }
        __syncthreads();
        int e = (blk - 768) * 256 + tid;
        float4 a = *(const float4*)(ea + (size_t)e * 4);
        // store exp(score) as bf16: walker multiplies directly (no exp in hot path)
        esb[e] = f2bf(__expf(a.x * wsb[0] + a.y * wsb[1] + a.z * wsb[2] + a.w * wsb[3] + wsb[4]));
        int src = ei[e];
        int dst = ei[NEDGE + e];
        int pos = atomicAdd(&cnt[src], 1);
        if (pos < RCAP) keys[src * RCAP + pos] = (dst << 18) | e;
    }
}

// ---- per-row sort by (dst,e): one wave per row; mark dup dst dead (last-wins)
__global__ __launch_bounds__(256) void cpa_sortrows(const int* __restrict__ cnt,
                                                    int* __restrict__ keys) {
    int row  = blockIdx.x * 4 + (threadIdx.x >> 6);
    int lane = threadIdx.x & 63;
    int len  = min(cnt[row], RCAP);
    int base = row * RCAP;
    int v = (lane < len) ? keys[base + lane] : 0x7FFFFFFF;

    #pragma unroll
    for (int k = 2; k <= 64; k <<= 1) {
        #pragma unroll
        for (int j = k >> 1; j >= 1; j >>= 1) {
            int p = __shfl_xor(v, j);
            bool asc = (lane & k) == 0;
            bool low = (lane & j) == 0;
            v = (low == asc) ? min(v, p) : max(v, p);
        }
    }
    int nxt = __shfl_down(v, 1);
    bool dead = (lane + 1 < len) && ((v >> 18) == (nxt >> 18));
    if (lane < len) keys[base + lane] = v | (dead ? 0x80000000 : 0);
}

// ---- flash attention, swapped-operand 32x32x16 core, zero-exchange pack.
// r13 structure (verified 66.4us). Deltas this round: exp via fma + raw
// v_exp_f32 (-16 VALU/tile/wave, no libcall) and tree-sum lacc (dep chain
// 64->16 cyc). Canary: WRITE_SIZE must stay ~16.6MB (no spills).
__global__ __launch_bounds__(512, 4) void cpa_flash(
    const short* __restrict__ Xbf, const short* __restrict__ Ybt,
    const short* __restrict__ esb, const int* __restrict__ keys,
    const int* __restrict__ cnt,
    float* __restrict__ lsplit, short* __restrict__ Opart)
{
    __shared__ short XjT[2][64][128];                 // 32 KB, X j-tile dbuf
    __shared__ short Yt[2][128][64];                  // 32 KB, V^T tile dbuf [f][j-local]
    __shared__ unsigned swp[4][2][2][64][4];          // 16 KB, A-frag swap

    const int tid  = threadIdx.x;
    const int lane = tid & 63;
    const int w    = tid >> 6;
    const int l31  = lane & 31;
    const int lh   = lane >> 5;
    const int ig   = w >> 1;          // query group (32 rows)
    const int jg   = w & 1;           // key half / output f-half

    const int split = blockIdx.x;     // linear%8 -> one split per XCD
    const int ib    = blockIdx.y;
    const int i0 = ib * BR;
    const int jstart = split * (N_NODES / SPLITS);

    // Xi B-fragments (resident, natural layout)
    short8 xi[8];
    #pragma unroll
    for (int kf = 0; kf < 8; ++kf)
        xi[kf] = *(const short8*)(Xbf + (size_t)(i0 + ig * 32 + l31) * DX + kf * 16 + lh * 8);

    // staging constants (swizzled source, linear LDS dest)
    const int xr0 = w * 8 + (lane >> 4);
    const int xc  = lane & 15;
    const int xo0 = (xc ^ (xr0 & 15)) << 3;
    const int xr1 = xr0 + 4;
    const int xo1 = (xc ^ (xr1 & 15)) << 3;
    const int yr  = w * 16 + (lane >> 3);
    const int yo  = ((lane & 7) ^ (yr & 7)) << 3;
    const int yr2 = yr + 8;
    const int yo2 = ((lane & 7) ^ (yr2 & 7)) << 3;

    // prologue: stage tile 0 into buffer 0
    gload_lds16(Xbf + (size_t)(jstart + xr0) * DX + xo0, &XjT[0][w * 8][0]);
    gload_lds16(Xbf + (size_t)(jstart + xr1) * DX + xo1, &XjT[0][w * 8 + 4][0]);
    gload_lds16(Ybt + (size_t)yr * N_NODES + jstart + yo,   &Yt[0][w * 16][0]);
    gload_lds16(Ybt + (size_t)yr2 * N_NODES + jstart + yo2, &Yt[0][w * 16 + 8][0]);

    // walker: lanes (l31, l31+32) walk row i0+ig*32+l31, filtered by lh parity.
    // Binary search for first key with dst >= jstart (<=6 dependent loads).
    const int myrow = i0 + ig * 32 + l31;
    const int base  = myrow * RCAP;
    const int len   = min(cnt[myrow], RCAP);
    int lo = 0, hi = len;
    while (lo < hi) {
        int mid = (lo + hi) >> 1;
        int d = (keys[base + mid] >> 18) & 0x1FFF;
        if (d < jstart) lo = mid + 1; else hi = mid;
    }
    int cur  = base + lo;
    int rend = base + len;
    int kcur = 0;
    if (cur < rend) kcur = keys[cur];

    f32x16 O0, O1;
    float lacc = 0.f;
    #pragma unroll
    for (int r = 0; r < 16; ++r) { O0[r] = 0.f; O1[r] = 0.f; }

    for (int tt = 0; tt < TILES; ++tt) {
        const int j0 = jstart + tt * BC;
        const int bb = tt & 1;

        __syncthreads();   // drains tile tt staging (issued one full tile ago)

        // stage next tile into the other buffers (in flight across this whole tile)
        if (tt + 1 < TILES) {
            gload_lds16(Xbf + (size_t)((j0 + BC) + xr0) * DX + xo0, &XjT[bb ^ 1][w * 8][0]);
            gload_lds16(Xbf + (size_t)((j0 + BC) + xr1) * DX + xo1, &XjT[bb ^ 1][w * 8 + 4][0]);
            gload_lds16(Ybt + (size_t)yr * N_NODES + (j0 + BC) + yo,   &Yt[bb ^ 1][w * 16][0]);
            gload_lds16(Ybt + (size_t)yr2 * N_NODES + (j0 + BC) + yo2, &Yt[bb ^ 1][w * 16 + 8][0]);
        }
        __builtin_amdgcn_sched_barrier(0);

        // S' = Xj . Xi^T (lane col = query i, regs = j rows)
        const int rr_ = jg * 32 + l31;
        f32x16 S;
        #pragma unroll
        for (int r = 0; r < 16; ++r) S[r] = 0.f;
        __builtin_amdgcn_s_setprio(1);
        #pragma unroll
        for (int kf = 0; kf < 8; ++kf) {
            short8 af = *(const short8*)&XjT[bb][rr_][((kf * 2 + lh) ^ (rr_ & 15)) << 3];
            S = __builtin_amdgcn_mfma_f32_32x32x16_bf16(af, xi[kf], S, 0, 0, 0);
        }
        __builtin_amdgcn_s_setprio(0);

        // softmax row in registers: p = 2^(S*log2e - 66*log2e), raw v_exp
        f32x16 p;
        #pragma unroll
        for (int r = 0; r < 16; ++r)
            p[r] = exp2_raw(__builtin_fmaf(S[r], L2E, -MSH2));

        // edge bias: keys with dst in [wlo, wlo+32); esb holds exp(score) bf16
        {
            const int wlo  = j0 + jg * 32;
            const int wend = wlo + 32;
            while (cur < rend) {
                int dst = (kcur >> 18) & 0x1FFF;
                if (dst >= wend) break;
                int kk = kcur;
                ++cur;
                if (cur < rend) kcur = keys[cur];
                int jl = dst - wlo;
                if (kk >= 0 && jl >= 0 && ((jl >> 2) & 1) == lh) {
                    float m = bf2f(esb[kk & 0x3FFFF]);
                    int sel = (jl & 3) | ((jl >> 3) << 2);
                    #pragma unroll
                    for (int r = 0; r < 16; ++r)
                        if (r == sel) p[r] *= m;
                }
            }
        }

        // l accumulation: pairwise tree (depth 4) instead of 16-deep serial chain
        {
            float s0 = (p[0] + p[1]) + (p[2] + p[3]);
            float s1 = (p[4] + p[5]) + (p[6] + p[7]);
            float s2 = (p[8] + p[9]) + (p[10] + p[11]);
            float s3 = (p[12] + p[13]) + (p[14] + p[15]);
            lacc += (s0 + s1) + (s2 + s3);
        }

        // pack P->bf16: pi-permuted Ybt makes these the PV A-frags directly
        union FU { unsigned u[4]; short8 s; int4 v; };
        FU F0, F1;
        F0.u[0] = cvtpk_bf16(p[0], p[1]);   F0.u[1] = cvtpk_bf16(p[2], p[3]);
        F0.u[2] = cvtpk_bf16(p[4], p[5]);   F0.u[3] = cvtpk_bf16(p[6], p[7]);
        F1.u[0] = cvtpk_bf16(p[8], p[9]);   F1.u[1] = cvtpk_bf16(p[10], p[11]);
        F1.u[2] = cvtpk_bf16(p[12], p[13]); F1.u[3] = cvtpk_bf16(p[14], p[15]);

        // publish to jg-partner
        *(int4*)&swp[ig][jg][0][lane][0] = F0.v;
        *(int4*)&swp[ig][jg][1][lane][0] = F1.v;

        // own-half PV (overlaps other waves' softmax tail)
        const int fA = jg * 64 + l31;
        const int fB = fA + 32;
        __builtin_amdgcn_s_setprio(1);
        #pragma unroll
        for (int sl = 0; sl < 2; ++sl) {
            short8 ao = sl ? F1.s : F0.s;
            const int co_o = jg * 4 + sl * 2 + lh;
            short8 b0o = *(const short8*)&Yt[bb][fA][(co_o ^ (fA & 7)) << 3];
            short8 b1o = *(const short8*)&Yt[bb][fB][(co_o ^ (fB & 7)) << 3];
            O0 = __builtin_amdgcn_mfma_f32_32x32x16_bf16(ao, b0o, O0, 0, 0, 0);
            O1 = __builtin_amdgcn_mfma_f32_32x32x16_bf16(ao, b1o, O1, 0, 0, 0);
        }
        __builtin_amdgcn_s_setprio(0);

        // swap barrier: DS-visibility only; staging vmcnt stays in flight
        asm volatile("s_waitcnt lgkmcnt(0)" ::: "memory");
        __builtin_amdgcn_s_barrier();
        __builtin_amdgcn_sched_barrier(0);

        // partner-half PV
        __builtin_amdgcn_s_setprio(1);
        #pragma unroll
        for (int sl = 0; sl < 2; ++sl) {
            short8 at = *(const short8*)&swp[ig][jg ^ 1][sl][lane][0];
            const int co_t = (jg ^ 1) * 4 + sl * 2 + lh;
            short8 b0t = *(const short8*)&Yt[bb][fA][(co_t ^ (fA & 7)) << 3];
            short8 b1t = *(const short8*)&Yt[bb][fB][(co_t ^ (fB & 7)) << 3];
            O0 = __builtin_amdgcn_mfma_f32_32x32x16_bf16(at, b0t, O0, 0, 0, 0);
            O1 = __builtin_amdgcn_mfma_f32_32x32x16_bf16(at, b1t, O1, 0, 0, 0);
        }
        __builtin_amdgcn_s_setprio(0);
        // no end barrier: XjT/Yt double-buffered; swp WAR covered by next __syncthreads
    }

    // epilogue: l cross-half + cross-jg merge (swp reused as scratch after sync)
    lacc += __shfl_xor(lacc, 32);
    __syncthreads();
    float* lmbuf = (float*)&swp[0][0][0][0][0];
    if (jg == 1 && lane < 32) lmbuf[ig * 32 + l31] = lacc;
    __syncthreads();
    if (jg == 0 && lane < 32)
        lsplit[(size_t)split * N_NODES + i0 + ig * 32 + l31] = lacc + lmbuf[ig * 32 + l31];

    #pragma unroll
    for (int r = 0; r < 16; ++r) {
        int row = ig * 32 + 4 * lh + (r & 3) + 8 * (r >> 2);
        size_t base2 = ((size_t)split * N_NODES + i0 + row) * DX;
        Opart[base2 + jg * 64 + l31]      = f2bf(O0[r]);
        Opart[base2 + jg * 64 + 32 + l31] = f2bf(O1[r]);
    }
}

// ---- merge splits + normalize, vectorized: 8 cols/thread, short8 reads
__global__ __launch_bounds__(256) void cpa_merge(const float* __restrict__ lsplit,
                                                 const short* __restrict__ Opart,
                                                 float* __restrict__ out) {
    int gid = blockIdx.x * 256 + threadIdx.x;   // N*16 units
    int i  = gid >> 4;
    int c8 = (gid & 15) << 3;
    float den = 0.f;
    float num[8];
    #pragma unroll
    for (int q = 0; q < 8; ++q) num[q] = 0.f;
    #pragma unroll
    for (int s = 0; s < SPLITS; ++s) {
        den += lsplit[(size_t)s * N_NODES + i];
        short8 v = *(const short8*)(Opart + ((size_t)s * N_NODES + i) * DX + c8);
        #pragma unroll
        for (int q = 0; q < 8; ++q) num[q] += bf2f(v[q]);
    }
    float inv = 1.0f / den;
    float4 o0, o1;
    o0.x = num[0] * inv; o0.y = num[1] * inv; o0.z = num[2] * inv; o0.w = num[3] * inv;
    o1.x = num[4] * inv; o1.y = num[5] * inv; o1.z = num[6] * inv; o1.w = num[7] * inv;
    float* dst = (c8 < 64) ? (out + (size_t)i * 64 + c8)
                           : (out + (size_t)N_NODES * 64 + (size_t)i * 64 + (c8 - 64));
    *(float4*)dst = o0;
    *(float4*)(dst + 4) = o1;
}

extern "C" void kernel_launch(void* const* d_in, const int* in_sizes, int n_in,
                              void* d_out, int out_size, void* d_ws, size_t ws_size,
                              hipStream_t stream)
{
    const float* mag   = (const float*)d_in[0];
    const float* phase = (const float*)d_in[1];
    const int*   ei    = (const int*)d_in[2];     // edge_index [2][E] (int32 per harness)
    const float* ea    = (const float*)d_in[3];
    const float* W     = (const float*)d_in[4];
    const float* b     = (const float*)d_in[5];
    float* out = (float*)d_out;

    char* ws = (char*)d_ws;
    short* Xbf    = (short*)(ws + 0);               // 2 MB (natural feature layout)
    short* Ybt    = (short*)(ws + 2097152);         // 2 MB (pi-permuted columns)
    short* esb    = (short*)(ws + 4194304);         // 512 KB (exp(edge score), bf16)
    int*   cnt    = (int*)  (ws + 4718592);         // 32 KB (dense)
    int*   keys   = (int*)  (ws + 5242880);         // 2 MB (8192 rows x 64 bins)
    float* lsplit = (float*)(ws + 7373056);         // 256 KB (8 splits)
    short* Opart  = (short*)(ws + 7635200);         // 16 MB (bf16, 8 splits)

    (void)hipMemsetAsync(cnt, 0, N_NODES * sizeof(int), stream);
    cpa_prep_all<<<512 + 256 + NEDGE / 256, 256, 0, stream>>>(mag, phase, ei, ea, W, b,
                                                              Xbf, Ybt, esb, cnt, keys);
    cpa_sortrows<<<N_NODES / 4, 256, 0, stream>>>(cnt, keys);
    cpa_flash<<<dim3(SPLITS, N_NODES / BR), 512, 0, stream>>>(Xbf, Ybt, esb, keys, cnt,
                                                              lsplit, Opart);
    cpa_merge<<<N_NODES * 16 / 256, 256, 0, stream>>>(lsplit, Opart, out);
}

// Round 15
// 147.420 us; speedup vs baseline: 1.0443x; 1.0443x over previous
//
#include <hip/hip_runtime.h>
#include <hip/hip_bf16.h>
#include <cstdint>

#define N_NODES 8192
#define DDIM    64
#define DX      128
#define NEDGE   262144
#define BR      128                       // query rows per block (8 waves)
#define BC      64                        // key/value columns per tile
#define SPLITS  8
#define TILES   (N_NODES / BC / SPLITS)   // 16
#define RCAP    64                        // per-row edge bin capacity
#define MSHIFT  66.0f                     // fixed softmax shift: raw scores < 64 always

typedef float f32x16 __attribute__((ext_vector_type(16)));
typedef short short8 __attribute__((ext_vector_type(8)));
typedef short short4v __attribute__((ext_vector_type(4)));

__device__ __forceinline__ short f2bf(float f) {
    union { float f; uint32_t u; } v; v.f = f;
    uint32_t u = v.u;
    uint32_t r = (u + 0x7FFFu + ((u >> 16) & 1u)) >> 16;
    return (short)r;
}
__device__ __forceinline__ float bf2f(short s) {
    union { uint32_t u; float f; } v;
    v.u = ((uint32_t)(uint16_t)s) << 16;
    return v.f;
}
__device__ __forceinline__ unsigned cvtpk_bf16(float lo, float hi) {
    unsigned r;
    asm("v_cvt_pk_bf16_f32 %0, %1, %2" : "=v"(r) : "v"(lo), "v"(hi));
    return r;
}
__device__ __forceinline__ void gload_lds16(const short* g, short* l) {
    __builtin_amdgcn_global_load_lds(
        (const __attribute__((address_space(1))) unsigned int*)g,
        (__attribute__((address_space(3))) unsigned int*)l, 16, 0, 0);
}

// ---- fused prep: [0,512) X-build (vectorized), [512,768) Y-transpose,
// [768,1792) edge scores + binning.
// Xbf: natural feature order [cos(0..63) | sin(64..127)].
// Ybt: columns stored with j-bits 2<->3 swapped (pi involution) so the S' output
// registers feed PV A-fragments with zero cross-lane exchange (verified r3/6/9-13).
__global__ __launch_bounds__(256) void cpa_prep_all(
    const float* __restrict__ mag, const float* __restrict__ phase,
    const int* __restrict__ ei, const float* __restrict__ ea,
    const float* __restrict__ W, const float* __restrict__ b,
    short* __restrict__ Xbf, short* __restrict__ Ybt,
    short* __restrict__ esb, int* __restrict__ cnt,
    int* __restrict__ keys) {
    __shared__ short tile[64][65];
    __shared__ float wsb[5];
    const int blk = blockIdx.x;
    const int tid = threadIdx.x;
    if (blk < 512) {
        // X-build: 4 features/thread, float4 in, short4 out
        int idx4 = blk * 256 + tid;                // 0..131071
        int i  = idx4 >> 4;
        int dq = (idx4 & 15) << 2;
        float4 m4 = *(const float4*)(mag   + (size_t)i * 64 + dq);
        float4 p4 = *(const float4*)(phase + (size_t)i * 64 + dq);
        short4v c4, s4;
        c4[0] = f2bf(m4.x * __cosf(p4.x)); s4[0] = f2bf(m4.x * __sinf(p4.x));
        c4[1] = f2bf(m4.y * __cosf(p4.y)); s4[1] = f2bf(m4.y * __sinf(p4.y));
        c4[2] = f2bf(m4.z * __cosf(p4.z)); s4[2] = f2bf(m4.z * __sinf(p4.z));
        c4[3] = f2bf(m4.w * __cosf(p4.w)); s4[3] = f2bf(m4.w * __sinf(p4.w));
        *(short4v*)(Xbf + (size_t)i * DX + dq)      = c4;
        *(short4v*)(Xbf + (size_t)i * DX + 64 + dq) = s4;
    } else if (blk < 768) {
        int bb = blk - 512;
        int bi = bb >> 1;
        int bc = bb & 1;
        int i0 = bi * 64;
        const float* src = bc ? phase : mag;
        for (int itr = 0; itr < 16; ++itr) {
            int idx = tid + itr * 256;             // 0..4095
            int ii = idx >> 6, cc = idx & 63;
            tile[ii][cc] = f2bf(src[(size_t)(i0 + ii) * 64 + cc]);
        }
        __syncthreads();
        for (int itr = 0; itr < 16; ++itr) {
            int idx = tid + itr * 256;
            int cc = idx >> 6, ii = idx & 63;
            int jp = (ii & 51) | ((ii & 4) << 1) | ((ii & 8) >> 1);  // swap j bits 2,3
            Ybt[(size_t)(bc * 64 + cc) * N_NODES + i0 + jp] = tile[ii][cc];
        }
    } else {
        if (tid < 64) {
            float w0 = W[tid * 4 + 0], w1 = W[tid * 4 + 1];
            float w2 = W[tid * 4 + 2], w3 = W[tid * 4 + 3];
            float bb = b[tid];
            #pragma unroll
            for (int o = 32; o > 0; o >>= 1) {
                w0 += __shfl_down(w0, o);
                w1 += __shfl_down(w1, o);
                w2 += __shfl_down(w2, o);
                w3 += __shfl_down(w3, o);
                bb += __shfl_down(bb, o);
            }
            if (tid == 0) { wsb[0] = w0; wsb[1] = w1; wsb[2] = w2; wsb[3] = w3; wsb[4] = bb; }
        }
        __syncthreads();
        int e = (blk - 768) * 256 + tid;
        float4 a = *(const float4*)(ea + (size_t)e * 4);
        // store exp(score) as bf16: walker multiplies directly (no exp in hot path)
        esb[e] = f2bf(__expf(a.x * wsb[0] + a.y * wsb[1] + a.z * wsb[2] + a.w * wsb[3] + wsb[4]));
        int src = ei[e];
        int dst = ei[NEDGE + e];
        int pos = atomicAdd(&cnt[src], 1);
        if (pos < RCAP) keys[src * RCAP + pos] = (dst << 18) | e;
    }
}

// ---- per-row sort by (dst,e): one wave per row; mark dup dst dead (last-wins)
__global__ __launch_bounds__(256) void cpa_sortrows(const int* __restrict__ cnt,
                                                    int* __restrict__ keys) {
    int row  = blockIdx.x * 4 + (threadIdx.x >> 6);
    int lane = threadIdx.x & 63;
    int len  = min(cnt[row], RCAP);
    int base = row * RCAP;
    int v = (lane < len) ? keys[base + lane] : 0x7FFFFFFF;

    #pragma unroll
    for (int k = 2; k <= 64; k <<= 1) {
        #pragma unroll
        for (int j = k >> 1; j >= 1; j >>= 1) {
            int p = __shfl_xor(v, j);
            bool asc = (lane & k) == 0;
            bool low = (lane & j) == 0;
            v = (low == asc) ? min(v, p) : max(v, p);
        }
    }
    int nxt = __shfl_down(v, 1);
    bool dead = (lane + 1 < len) && ((v >> 18) == (nxt >> 18));
    if (lane < len) keys[base + lane] = v | (dead ? 0x80000000 : 0);
}

// ---- flash attention, swapped-operand 32x32x16 core, zero-exchange pack.
// The twice-verified 66.4us configuration (r10/r11/r13 main loop, bf16 es,
// dense cnt, __expf softmax -- both alternative exp forms spill: r8 libcall,
// r14 raw-asm; WRITE_SIZE 16640 is the no-spill canary).
__global__ __launch_bounds__(512, 4) void cpa_flash(
    const short* __restrict__ Xbf, const short* __restrict__ Ybt,
    const short* __restrict__ esb, const int* __restrict__ keys,
    const int* __restrict__ cnt,
    float* __restrict__ lsplit, short* __restrict__ Opart)
{
    __shared__ short XjT[2][64][128];                 // 32 KB, X j-tile dbuf
    __shared__ short Yt[2][128][64];                  // 32 KB, V^T tile dbuf [f][j-local]
    __shared__ unsigned swp[4][2][2][64][4];          // 16 KB, A-frag swap

    const int tid  = threadIdx.x;
    const int lane = tid & 63;
    const int w    = tid >> 6;
    const int l31  = lane & 31;
    const int lh   = lane >> 5;
    const int ig   = w >> 1;          // query group (32 rows)
    const int jg   = w & 1;           // key half / output f-half

    const int split = blockIdx.x;     // linear%8 -> one split per XCD
    const int ib    = blockIdx.y;
    const int i0 = ib * BR;
    const int jstart = split * (N_NODES / SPLITS);

    // Xi B-fragments (resident, natural layout)
    short8 xi[8];
    #pragma unroll
    for (int kf = 0; kf < 8; ++kf)
        xi[kf] = *(const short8*)(Xbf + (size_t)(i0 + ig * 32 + l31) * DX + kf * 16 + lh * 8);

    // staging constants (swizzled source, linear LDS dest)
    const int xr0 = w * 8 + (lane >> 4);
    const int xc  = lane & 15;
    const int xo0 = (xc ^ (xr0 & 15)) << 3;
    const int xr1 = xr0 + 4;
    const int xo1 = (xc ^ (xr1 & 15)) << 3;
    const int yr  = w * 16 + (lane >> 3);
    const int yo  = ((lane & 7) ^ (yr & 7)) << 3;
    const int yr2 = yr + 8;
    const int yo2 = ((lane & 7) ^ (yr2 & 7)) << 3;

    // prologue: stage tile 0 into buffer 0
    gload_lds16(Xbf + (size_t)(jstart + xr0) * DX + xo0, &XjT[0][w * 8][0]);
    gload_lds16(Xbf + (size_t)(jstart + xr1) * DX + xo1, &XjT[0][w * 8 + 4][0]);
    gload_lds16(Ybt + (size_t)yr * N_NODES + jstart + yo,   &Yt[0][w * 16][0]);
    gload_lds16(Ybt + (size_t)yr2 * N_NODES + jstart + yo2, &Yt[0][w * 16 + 8][0]);

    // walker: lanes (l31, l31+32) walk row i0+ig*32+l31, filtered by lh parity.
    // Binary search for first key with dst >= jstart (<=6 dependent loads).
    const int myrow = i0 + ig * 32 + l31;
    const int base  = myrow * RCAP;
    const int len   = min(cnt[myrow], RCAP);
    int lo = 0, hi = len;
    while (lo < hi) {
        int mid = (lo + hi) >> 1;
        int d = (keys[base + mid] >> 18) & 0x1FFF;
        if (d < jstart) lo = mid + 1; else hi = mid;
    }
    int cur  = base + lo;
    int rend = base + len;
    int kcur = 0;
    if (cur < rend) kcur = keys[cur];

    f32x16 O0, O1;
    float lacc = 0.f;
    #pragma unroll
    for (int r = 0; r < 16; ++r) { O0[r] = 0.f; O1[r] = 0.f; }

    for (int tt = 0; tt < TILES; ++tt) {
        const int j0 = jstart + tt * BC;
        const int bb = tt & 1;

        __syncthreads();   // drains tile tt staging (issued one full tile ago)

        // stage next tile into the other buffers (in flight across this whole tile)
        if (tt + 1 < TILES) {
            gload_lds16(Xbf + (size_t)((j0 + BC) + xr0) * DX + xo0, &XjT[bb ^ 1][w * 8][0]);
            gload_lds16(Xbf + (size_t)((j0 + BC) + xr1) * DX + xo1, &XjT[bb ^ 1][w * 8 + 4][0]);
            gload_lds16(Ybt + (size_t)yr * N_NODES + (j0 + BC) + yo,   &Yt[bb ^ 1][w * 16][0]);
            gload_lds16(Ybt + (size_t)yr2 * N_NODES + (j0 + BC) + yo2, &Yt[bb ^ 1][w * 16 + 8][0]);
        }
        __builtin_amdgcn_sched_barrier(0);

        // S' = Xj . Xi^T (lane col = query i, regs = j rows)
        const int rr_ = jg * 32 + l31;
        f32x16 S;
        #pragma unroll
        for (int r = 0; r < 16; ++r) S[r] = 0.f;
        __builtin_amdgcn_s_setprio(1);
        #pragma unroll
        for (int kf = 0; kf < 8; ++kf) {
            short8 af = *(const short8*)&XjT[bb][rr_][((kf * 2 + lh) ^ (rr_ & 15)) << 3];
            S = __builtin_amdgcn_mfma_f32_32x32x16_bf16(af, xi[kf], S, 0, 0, 0);
        }
        __builtin_amdgcn_s_setprio(0);

        // softmax row in registers
        f32x16 p;
        #pragma unroll
        for (int r = 0; r < 16; ++r) p[r] = __expf(S[r] - MSHIFT);

        // edge bias: keys with dst in [wlo, wlo+32); esb holds exp(score) bf16
        {
            const int wlo  = j0 + jg * 32;
            const int wend = wlo + 32;
            while (cur < rend) {
                int dst = (kcur >> 18) & 0x1FFF;
                if (dst >= wend) break;
                int kk = kcur;
                ++cur;
                if (cur < rend) kcur = keys[cur];
                int jl = dst - wlo;
                if (kk >= 0 && jl >= 0 && ((jl >> 2) & 1) == lh) {
                    float m = bf2f(esb[kk & 0x3FFFF]);
                    int sel = (jl & 3) | ((jl >> 3) << 2);
                    #pragma unroll
                    for (int r = 0; r < 16; ++r)
                        if (r == sel) p[r] *= m;
                }
            }
        }

        // l accumulation (f32 direct sum; verified rounds 3/7-13)
        #pragma unroll
        for (int r = 0; r < 16; ++r) lacc += p[r];

        // pack P->bf16: pi-permuted Ybt makes these the PV A-frags directly
        union FU { unsigned u[4]; short8 s; int4 v; };
        FU F0, F1;
        F0.u[0] = cvtpk_bf16(p[0], p[1]);   F0.u[1] = cvtpk_bf16(p[2], p[3]);
        F0.u[2] = cvtpk_bf16(p[4], p[5]);   F0.u[3] = cvtpk_bf16(p[6], p[7]);
        F1.u[0] = cvtpk_bf16(p[8], p[9]);   F1.u[1] = cvtpk_bf16(p[10], p[11]);
        F1.u[2] = cvtpk_bf16(p[12], p[13]); F1.u[3] = cvtpk_bf16(p[14], p[15]);

        // publish to jg-partner
        *(int4*)&swp[ig][jg][0][lane][0] = F0.v;
        *(int4*)&swp[ig][jg][1][lane][0] = F1.v;

        // own-half PV (overlaps other waves' softmax tail)
        const int fA = jg * 64 + l31;
        const int fB = fA + 32;
        __builtin_amdgcn_s_setprio(1);
        #pragma unroll
        for (int sl = 0; sl < 2; ++sl) {
            short8 ao = sl ? F1.s : F0.s;
            const int co_o = jg * 4 + sl * 2 + lh;
            short8 b0o = *(const short8*)&Yt[bb][fA][(co_o ^ (fA & 7)) << 3];
            short8 b1o = *(const short8*)&Yt[bb][fB][(co_o ^ (fB & 7)) << 3];
            O0 = __builtin_amdgcn_mfma_f32_32x32x16_bf16(ao, b0o, O0, 0, 0, 0);
            O1 = __builtin_amdgcn_mfma_f32_32x32x16_bf16(ao, b1o, O1, 0, 0, 0);
        }
        __builtin_amdgcn_s_setprio(0);

        // swap barrier: DS-visibility only; staging vmcnt stays in flight
        asm volatile("s_waitcnt lgkmcnt(0)" ::: "memory");
        __builtin_amdgcn_s_barrier();
        __builtin_amdgcn_sched_barrier(0);

        // partner-half PV
        __builtin_amdgcn_s_setprio(1);
        #pragma unroll
        for (int sl = 0; sl < 2; ++sl) {
            short8 at = *(const short8*)&swp[ig][jg ^ 1][sl][lane][0];
            const int co_t = (jg ^ 1) * 4 + sl * 2 + lh;
            short8 b0t = *(const short8*)&Yt[bb][fA][(co_t ^ (fA & 7)) << 3];
            short8 b1t = *(const short8*)&Yt[bb][fB][(co_t ^ (fB & 7)) << 3];
            O0 = __builtin_amdgcn_mfma_f32_32x32x16_bf16(at, b0t, O0, 0, 0, 0);
            O1 = __builtin_amdgcn_mfma_f32_32x32x16_bf16(at, b1t, O1, 0, 0, 0);
        }
        __builtin_amdgcn_s_setprio(0);
        // no end barrier: XjT/Yt double-buffered; swp WAR covered by next __syncthreads
    }

    // epilogue: l cross-half + cross-jg merge (swp reused as scratch after sync)
    lacc += __shfl_xor(lacc, 32);
    __syncthreads();
    float* lmbuf = (float*)&swp[0][0][0][0][0];
    if (jg == 1 && lane < 32) lmbuf[ig * 32 + l31] = lacc;
    __syncthreads();
    if (jg == 0 && lane < 32)
        lsplit[(size_t)split * N_NODES + i0 + ig * 32 + l31] = lacc + lmbuf[ig * 32 + l31];

    #pragma unroll
    for (int r = 0; r < 16; ++r) {
        int row = ig * 32 + 4 * lh + (r & 3) + 8 * (r >> 2);
        size_t base2 = ((size_t)split * N_NODES + i0 + row) * DX;
        Opart[base2 + jg * 64 + l31]      = f2bf(O0[r]);
        Opart[base2 + jg * 64 + 32 + l31] = f2bf(O1[r]);
    }
}

// ---- merge splits + normalize, vectorized: 8 cols/thread, short8 reads
__global__ __launch_bounds__(256) void cpa_merge(const float* __restrict__ lsplit,
                                                 const short* __restrict__ Opart,
                                                 float* __restrict__ out) {
    int gid = blockIdx.x * 256 + threadIdx.x;   // N*16 units
    int i  = gid >> 4;
    int c8 = (gid & 15) << 3;
    float den = 0.f;
    float num[8];
    #pragma unroll
    for (int q = 0; q < 8; ++q) num[q] = 0.f;
    #pragma unroll
    for (int s = 0; s < SPLITS; ++s) {
        den += lsplit[(size_t)s * N_NODES + i];
        short8 v = *(const short8*)(Opart + ((size_t)s * N_NODES + i) * DX + c8);
        #pragma unroll
        for (int q = 0; q < 8; ++q) num[q] += bf2f(v[q]);
    }
    float inv = 1.0f / den;
    float4 o0, o1;
    o0.x = num[0] * inv; o0.y = num[1] * inv; o0.z = num[2] * inv; o0.w = num[3] * inv;
    o1.x = num[4] * inv; o1.y = num[5] * inv; o1.z = num[6] * inv; o1.w = num[7] * inv;
    float* dst = (c8 < 64) ? (out + (size_t)i * 64 + c8)
                           : (out + (size_t)N_NODES * 64 + (size_t)i * 64 + (c8 - 64));
    *(float4*)dst = o0;
    *(float4*)(dst + 4) = o1;
}

extern "C" void kernel_launch(void* const* d_in, const int* in_sizes, int n_in,
                              void* d_out, int out_size, void* d_ws, size_t ws_size,
                              hipStream_t stream)
{
    const float* mag   = (const float*)d_in[0];
    const float* phase = (const float*)d_in[1];
    const int*   ei    = (const int*)d_in[2];     // edge_index [2][E] (int32 per harness)
    const float* ea    = (const float*)d_in[3];
    const float* W     = (const float*)d_in[4];
    const float* b     = (const float*)d_in[5];
    float* out = (float*)d_out;

    char* ws = (char*)d_ws;
    short* Xbf    = (short*)(ws + 0);               // 2 MB (natural feature layout)
    short* Ybt    = (short*)(ws + 2097152);         // 2 MB (pi-permuted columns)
    short* esb    = (short*)(ws + 4194304);         // 512 KB (exp(edge score), bf16)
    int*   cnt    = (int*)  (ws + 4718592);         // 32 KB (dense)
    int*   keys   = (int*)  (ws + 5242880);         // 2 MB (8192 rows x 64 bins)
    float* lsplit = (float*)(ws + 7373056);         // 256 KB (8 splits)
    short* Opart  = (short*)(ws + 7635200);         // 16 MB (bf16, 8 splits)

    (void)hipMemsetAsync(cnt, 0, N_NODES * sizeof(int), stream);
    cpa_prep_all<<<512 + 256 + NEDGE / 256, 256, 0, stream>>>(mag, phase, ei, ea, W, b,
                                                              Xbf, Ybt, esb, cnt, keys);
    cpa_sortrows<<<N_NODES / 4, 256, 0, stream>>>(cnt, keys);
    cpa_flash<<<dim3(SPLITS, N_NODES / BR), 512, 0, stream>>>(Xbf, Ybt, esb, keys, cnt,
                                                              lsplit, Opart);
    cpa_merge<<<N_NODES * 16 / 256, 256, 0, stream>>>(lsplit, Opart, out);
}